// Round 13
// baseline (298.641 us; speedup 1.0000x reference)
//
#include <hip/hip_runtime.h>
#include <math.h>

#define NB_B 2
#define NB_N 4096
#define NB_DIM 1024
#define NB_H 16
#define NB_D 64
#define NB_CTX 3072
#define NSPLIT 4
// 0.125 * log2(e): folds softmax base-2 conversion into q scale
#define QSCALE 0.18033688011112042f
#define NEGF -3.0e38f

typedef __attribute__((ext_vector_type(8))) short short8;
typedef __attribute__((ext_vector_type(4))) short s4v;
typedef __attribute__((ext_vector_type(4))) float f32x4;
typedef __fp16 fp16x2 __attribute__((ext_vector_type(2)));

#if __has_builtin(__builtin_amdgcn_mfma_f32_16x16x16bf16_1k)
__device__ __forceinline__ f32x4 mfma16(s4v a, s4v b, f32x4 c) {
  return __builtin_amdgcn_mfma_f32_16x16x16bf16_1k(a, b, c, 0, 0, 0);
}
#else
__device__ __forceinline__ f32x4 mfma16(s4v a, s4v b, f32x4 c) {
  f32x4 d;
  asm volatile("v_mfma_f32_16x16x16_bf16 %0, %1, %2, %3"
               : "=v"(d) : "v"(a), "v"(b), "v"(c));
  return d;
}
#endif

__device__ __forceinline__ unsigned short f2bf(float f) {
  union { float f; unsigned u; } v; v.f = f;
  unsigned r = v.u + 0x7fffu + ((v.u >> 16) & 1u);
  return (unsigned short)(r >> 16);
}

// packed f32x2 -> bf16x2 (RNE), 1 op instead of and/and/perm
__device__ __forceinline__ unsigned int cvtpk(float a, float b) {
  unsigned int r;
  asm("v_cvt_pk_bf16_f32 %0, %1, %2" : "=v"(r) : "v"(a), "v"(b));
  return r;
}

// packed f32x2 -> f16x2 (RTZ)
__device__ __forceinline__ unsigned int pkh(float a, float b) {
  union { fp16x2 h; unsigned int u; } cv;
  cv.h = __builtin_amdgcn_cvt_pkrtz(a, b);
  return cv.u;
}

__device__ __forceinline__ void async16(const void* g, void* l) {
  typedef const unsigned int __attribute__((address_space(1)))* gas_t;
  typedef unsigned int __attribute__((address_space(3)))* las_t;
  __builtin_amdgcn_global_load_lds((gas_t)(unsigned long long)g,
                                   (las_t)(unsigned)(unsigned long long)l,
                                   16, 0, 0);
}

// ---------------- merged prep: conv_x | weight transpose | rope table ----------------
__global__ __launch_bounds__(256) void k_prep(
    const float* __restrict__ x,
    const float* __restrict__ Wq, const float* __restrict__ Wkv, const float* __restrict__ Wo,
    unsigned short* __restrict__ xb, unsigned short* __restrict__ WqkvT,
    unsigned short* __restrict__ WoT, float2* __restrict__ tab)
{
  __shared__ float tile[64][65];
  const int bx = blockIdx.x, tid = threadIdx.x;
  if (bx < 2048) {
    const float4* x4 = (const float4*)x;
    ushort4* xb4 = (ushort4*)xb;
    const int n4 = (NB_B * NB_N * NB_DIM) / 4;
    for (int i = bx * 256 + tid; i < n4; i += 2048 * 256) {
      float4 v = x4[i];
      ushort4 o;
      o.x = f2bf(v.x); o.y = f2bf(v.y); o.z = f2bf(v.z); o.w = f2bf(v.w);
      xb4[i] = o;
    }
  } else if (bx < 2816) {
    int idx = bx - 2048;
    int z = idx >> 8, rem = idx & 255;
    const float* W; unsigned short* out;
    if (z == 0)      { W = Wq;  out = WqkvT; }
    else if (z == 1) { W = Wkv; out = WqkvT + 1024 * 1024; }
    else             { W = Wo;  out = WoT; }
    int c0 = (rem & 15) * 64, k0 = (rem >> 4) * 64;
    int tx = tid & 63, ty = tid >> 6;
    #pragma unroll
    for (int i = 0; i < 16; ++i) {
      int k = ty + i * 4;
      tile[k][tx] = W[(long)(k0 + k) * 1024 + c0 + tx];
    }
    __syncthreads();
    #pragma unroll
    for (int i = 0; i < 16; ++i) {
      int c = ty + i * 4;
      out[(long)(c0 + c) * 1024 + k0 + tx] = f2bf(tile[tx][c]);
    }
  } else {
    int idx = (bx - 2816) * 256 + tid;   // [0, 131072)
    int n = idx >> 5, fi = idx & 31;
    float inv = exp2f(-(float)fi * (13.287712379549449f / 32.0f));
    float ang = (float)n * inv;
    float s, c;
    sincosf(ang, &s, &c);
    tab[idx] = make_float2(c, s);
  }
}

// ---------------- QKV GEMM, 2-phase double-buffered LDS (T3/T4 minimum) ----------------
// ONE barrier per K-step: stage next 32-col slab into buf[other] right after the
// barrier; its global_load_lds drains under the current slab's ds_read+MFMA and
// retires inside the NEXT barrier's conservative vmcnt(0) drain. Pair-unrolled
// K-loop (32 even steps) keeps all LDS addresses static. LDS 32 KB.
__global__ __launch_bounds__(256) void k_gemm_qkv(
    const unsigned short* __restrict__ A,
    const unsigned short* __restrict__ Bt,
    unsigned short* __restrict__ qf,
    unsigned short* __restrict__ lkvp,
    const float2* __restrict__ tab,
    const float* __restrict__ ln_g,
    const float* __restrict__ ln_b)
{
  __shared__ unsigned short As[2][128 * 32];
  __shared__ unsigned short Bs[2][128 * 32];
  const int tid = threadIdx.x;
  const int w = tid >> 6, lane = tid & 63;
  const int wr = w >> 1, wc = w & 1;
  const int quad = lane >> 4, l15 = lane & 15;
  const long tm = (long)blockIdx.y * 128, tn = (long)blockIdx.x * 128;
  const int K = 1024;

  f32x4 acc[4][4];
  #pragma unroll
  for (int i = 0; i < 4; ++i)
    #pragma unroll
    for (int j = 0; j < 4; ++j)
      acc[i][j] = (f32x4){0.f, 0.f, 0.f, 0.f};

  const unsigned short* Ag0 = A + (tm + w * 16 + (lane >> 2)) * K + (lane & 3) * 8;
  const unsigned short* Bg0 = Bt + (tn + w * 16 + (lane >> 2)) * K + (lane & 3) * 8;
  const unsigned short* Ag1 = Ag0 + (long)64 * K;
  const unsigned short* Bg1 = Bg0 + (long)64 * K;
  const int so0 = (w * 16) * 32;          // this wave's slab offsets within a buffer
  const int so1 = (64 + w * 16) * 32;

#define QKV_STAGE(b, k)                         \
  async16(Ag0 + (k), &As[b][so0]);              \
  async16(Ag1 + (k), &As[b][so1]);              \
  async16(Bg0 + (k), &Bs[b][so0]);              \
  async16(Bg1 + (k), &Bs[b][so1]);

#define QKV_CONSUME(b)                                                          \
  {                                                                             \
    short8 af[4], bfr[4];                                                       \
    _Pragma("unroll")                                                           \
    for (int i = 0; i < 4; ++i)                                                 \
      af[i] = *(const short8*)&As[b][(wr * 64 + i * 16 + l15) * 32 + quad * 8]; \
    _Pragma("unroll")                                                           \
    for (int j = 0; j < 4; ++j)                                                 \
      bfr[j] = *(const short8*)&Bs[b][(wc * 64 + j * 16 + l15) * 32 + quad * 8];\
    __builtin_amdgcn_s_setprio(1);                                              \
    _Pragma("unroll")                                                           \
    for (int i = 0; i < 4; ++i)                                                 \
      _Pragma("unroll")                                                         \
      for (int j = 0; j < 4; ++j)                                               \
        acc[i][j] = __builtin_amdgcn_mfma_f32_16x16x32_bf16(af[i], bfr[j], acc[i][j], 0, 0, 0); \
    __builtin_amdgcn_s_setprio(0);                                              \
  }

  QKV_STAGE(0, 0);                        // prologue: first slab -> buf0
  for (int k0 = 0; k0 < K; k0 += 64) {
    __syncthreads();                      // buf0 staged loads drained; buf1 reads done
    if (k0 + 32 < K) { QKV_STAGE(1, k0 + 32); }
    QKV_CONSUME(0);
    __syncthreads();                      // buf1 staged loads drained; buf0 reads done
    if (k0 + 64 < K) { QKV_STAGE(0, k0 + 64); }
    QKV_CONSUME(1);
  }

  const int col_base = (int)tn + wc * 64;
  const bool is_q = col_base < 1024;
  const int hh = (col_base & 1023) >> 6;
  unsigned short* dst = is_q ? qf : lkvp;
  float g_ln[4], b_ln[4];
  #pragma unroll
  for (int j = 0; j < 4; ++j) { g_ln[j] = ln_g[j * 16 + l15]; b_ln[j] = ln_b[j * 16 + l15]; }

  const int row_base = (int)tm + wr * 64;
  #pragma unroll
  for (int i = 0; i < 4; ++i) {
    #pragma unroll
    for (int r = 0; r < 4; ++r) {
      const int row = row_base + i * 16 + quad * 4 + r;
      const int n = row & 4095, b = row >> 12;
      const float2 cs0 = tab[n * 32 + l15];
      const float2 cs1 = tab[n * 32 + 16 + l15];
      float val[4];
      #pragma unroll
      for (int j = 0; j < 4; ++j) {
        float t = acc[i][j][r], pt = acc[i][j ^ 2][r];
        float2 cs = (j & 1) ? cs1 : cs0;
        float rot = (j < 2) ? -pt : pt;
        val[j] = t * cs.x + rot * cs.y;
      }
      unsigned short* orow = dst + ((long)(b * 16 + hh) * NB_N + n) * 64;
      if (is_q) {
        #pragma unroll
        for (int j = 0; j < 4; ++j)
          orow[j * 16 + l15] = f2bf(val[j] * QSCALE);
      } else {
        float s = val[0] + val[1] + val[2] + val[3];
        #pragma unroll
        for (int o = 1; o < 16; o <<= 1) s += __shfl_xor(s, o);
        const float mu = s * 0.015625f;
        float dv[4], vs = 0.f;
        #pragma unroll
        for (int j = 0; j < 4; ++j) { dv[j] = val[j] - mu; vs += dv[j] * dv[j]; }
        #pragma unroll
        for (int o = 1; o < 16; o <<= 1) vs += __shfl_xor(vs, o);
        const float rr = rsqrtf(vs * 0.015625f + 1e-5f);
        #pragma unroll
        for (int j = 0; j < 4; ++j)
          orow[j * 16 + l15] = f2bf(dv[j] * rr * g_ln[j] + b_ln[j]);
      }
    }
  }
}

// ---------------- generic bf16 GEMM (final projection), 2-phase dbuf ----------------
__global__ __launch_bounds__(256) void k_gemm_bt(
    const unsigned short* __restrict__ A,
    const unsigned short* __restrict__ Bt,
    float* __restrict__ C,
    const float* __restrict__ bias,
    int K, int ldc)
{
  __shared__ unsigned short As[2][128 * 32];
  __shared__ unsigned short Bs[2][128 * 32];
  const int tid = threadIdx.x;
  const int w = tid >> 6, lane = tid & 63;
  const int wr = w >> 1, wc = w & 1;
  const int quad = lane >> 4, l15 = lane & 15;
  const long tm = (long)blockIdx.y * 128, tn = (long)blockIdx.x * 128;

  f32x4 acc[4][4];
  #pragma unroll
  for (int i = 0; i < 4; ++i)
    #pragma unroll
    for (int j = 0; j < 4; ++j)
      acc[i][j] = (f32x4){0.f, 0.f, 0.f, 0.f};

  const unsigned short* Ag0 = A + (tm + w * 16 + (lane >> 2)) * K + (lane & 3) * 8;
  const unsigned short* Bg0 = Bt + (tn + w * 16 + (lane >> 2)) * K + (lane & 3) * 8;
  const unsigned short* Ag1 = Ag0 + (long)64 * K;
  const unsigned short* Bg1 = Bg0 + (long)64 * K;
  const int so0 = (w * 16) * 32;
  const int so1 = (64 + w * 16) * 32;

  QKV_STAGE(0, 0);
  for (int k0 = 0; k0 < K; k0 += 64) {
    __syncthreads();
    if (k0 + 32 < K) { QKV_STAGE(1, k0 + 32); }
    QKV_CONSUME(0);
    __syncthreads();
    if (k0 + 64 < K) { QKV_STAGE(0, k0 + 64); }
    QKV_CONSUME(1);
  }

  #pragma unroll
  for (int j = 0; j < 4; ++j) {
    const long col = tn + wc * 64 + j * 16 + l15;
    const float bv = bias ? bias[col] : 0.0f;
    #pragma unroll
    for (int i = 0; i < 4; ++i) {
      #pragma unroll
      for (int r = 0; r < 4; ++r) {
        const long row = tm + wr * 64 + i * 16 + quad * 4 + r;
        C[row * ldc + col] = acc[i][j][r] + bv;
      }
    }
  }
}

// ---------------- flash attention (round-6 verified) + T1 XCD swizzle ----------------
// Stage at tile START (drains under compute) + f16 normalized Opart + T5
// setprio around MFMA clusters. Double-buffered K/V LDS with STATIC buffer
// addresses (tile loop unrolled x2, split boundaries forced even so no tail).
// ONE barrier per tile. Softmax: exp2 against wave-uniform reference miu (0 in
// practice), bf16 pack via v_cvt_pk_bf16_f32, row-sums li via a ones-A MFMA.
// Deferred-max guard: wave-uniform __any(mx>miu+8), exact rescale (never taken).
// T1: bijective chunked block-ID remap (grid 1792 = 8*224 exactly) so the 32
// consecutive logical blocks sharing one bh's K/V panel land on ONE XCD's L2.

#define NB_GRID (256 * NSPLIT + 768)     // 1792
#define NB_CHUNK (NB_GRID / 8)           // 224 (exact)

__device__ __forceinline__ void stage_kv(
    unsigned short* __restrict__ Ksn, unsigned short* __restrict__ Vtn,
    const int kp, const int sdc, const uint4& gA, const uint4& gB)
{
  *(uint4*)&Ksn[(2 * kp) * 72 + sdc * 8] = gA;
  *(uint4*)&Ksn[(2 * kp + 1) * 72 + sdc * 8] = gB;
  const unsigned int* wA = (const unsigned int*)&gA;
  const unsigned int* wB = (const unsigned int*)&gB;
  #pragma unroll
  for (int jw = 0; jw < 4; ++jw) {
    const unsigned int lo = __builtin_amdgcn_perm(wB[jw], wA[jw], 0x05040100u);
    const unsigned int hi = __builtin_amdgcn_perm(wB[jw], wA[jw], 0x07060302u);
    const int d0 = sdc * 8 + jw * 2;
    const int xo = (2 * kp) ^ (d0 & 56);   // (d0+1)&56 == d0&56 (d0 even)
    *(unsigned int*)&Vtn[d0 * 72 + xo] = lo;
    *(unsigned int*)&Vtn[(d0 + 1) * 72 + xo] = hi;
  }
}

#define NB_PACK(QG, SUB)                                               \
  _Pragma("unroll")                                                    \
  for (int k4 = 0; k4 < 4; ++k4) {                                     \
    const float p0 = __builtin_amdgcn_exp2f(st[QG][k4][0] SUB);        \
    const float p1 = __builtin_amdgcn_exp2f(st[QG][k4][1] SUB);        \
    const float p2 = __builtin_amdgcn_exp2f(st[QG][k4][2] SUB);        \
    const float p3 = __builtin_amdgcn_exp2f(st[QG][k4][3] SUB);        \
    pk[QG][k4][0] = cvtpk(p0, p1);                                     \
    pk[QG][k4][1] = cvtpk(p2, p3);                                     \
  }

__device__ __forceinline__ void attn_tile(
    const unsigned short* __restrict__ Ks, const unsigned short* __restrict__ Vt,
    unsigned short* __restrict__ Ksn, unsigned short* __restrict__ Vtn,
    const int kt, const int kt1, const int kstart, const bool latent, const int q0lat,
    const int w, const int quad, const int l15, const int kp, const int sdc,
    const unsigned short* __restrict__ kbase,
    uint4& gA, uint4& gB, const short8 (&qfr)[2][2],
    f32x4 (&ot)[2][4], f32x4 (&lacc)[2], float& miu, float& thr)
{
  const int key0 = kstart + kt * 64;
  __syncthreads();   // buf[cur] staged stores visible; buf[next] reads complete

  if (kt + 1 < kt1) {   // stage next tile into the OTHER buffer (drains under compute)
    stage_kv(Ksn, Vtn, kp, sdc, gA, gB);
    if (kt + 2 < kt1) { // prefetch tile kt+2 into regs
      const long k2 = (long)(key0 + 128);
      gA = *(const uint4*)(kbase + (k2 + 2 * kp) * 64 + sdc * 8);
      gB = *(const uint4*)(kbase + (k2 + 2 * kp + 1) * 64 + sdc * 8);
    }
  }

  // S^T[key][q]
  f32x4 st[2][4];
  #pragma unroll
  for (int qg = 0; qg < 2; ++qg)
    #pragma unroll
    for (int k4 = 0; k4 < 4; ++k4)
      st[qg][k4] = (f32x4){0.f, 0.f, 0.f, 0.f};
  __builtin_amdgcn_s_setprio(1);
  #pragma unroll
  for (int kc = 0; kc < 2; ++kc) {
    short8 kf[4];
    #pragma unroll
    for (int k4 = 0; k4 < 4; ++k4)
      kf[k4] = *(const short8*)&Ks[(k4 * 16 + l15) * 72 + kc * 32 + quad * 8];
    #pragma unroll
    for (int qg = 0; qg < 2; ++qg)
      #pragma unroll
      for (int k4 = 0; k4 < 4; ++k4)
        st[qg][k4] = __builtin_amdgcn_mfma_f32_16x16x32_bf16(kf[k4], qfr[qg][kc], st[qg][k4], 0, 0, 0);
  }
  __builtin_amdgcn_s_setprio(0);

  // causal mask among latents
  if (latent && key0 + 63 >= NB_CTX) {
    #pragma unroll
    for (int qg = 0; qg < 2; ++qg) {
      const int qrow = q0lat + w * 32 + qg * 16 + l15;
      #pragma unroll
      for (int k4 = 0; k4 < 4; ++k4)
        #pragma unroll
        for (int r = 0; r < 4; ++r) {
          const int kl = key0 + k4 * 16 + quad * 4 + r - NB_CTX;
          if (kl > qrow) st[qg][k4][r] = NEGF;
        }
    }
  }

  // tile max (guard only; off the exp->PV critical path)
  float mx = st[0][0][0];
  #pragma unroll
  for (int qg = 0; qg < 2; ++qg)
    #pragma unroll
    for (int k4 = 0; k4 < 4; ++k4)
      mx = fmaxf(mx, fmaxf(fmaxf(st[qg][k4][0], st[qg][k4][1]),
                           fmaxf(st[qg][k4][2], st[qg][k4][3])));

  // exp2 against wave-uniform reference; pack to bf16 pairs via cvt_pk
  unsigned int pk[2][4][2];
  if (miu == 0.f) {
    NB_PACK(0, )
    NB_PACK(1, )
  } else {
    NB_PACK(0, - miu)
    NB_PACK(1, - miu)
  }

  // O^T += V^T P^T ; li row-sums via ones-A MFMA (sums the same bf16 P)
  const s4v vones = { (short)0x3F80, (short)0x3F80, (short)0x3F80, (short)0x3F80 };
  __builtin_amdgcn_s_setprio(1);
  #pragma unroll
  for (int k4 = 0; k4 < 4; ++k4) {
    s4v vf[4];
    const int kb = k4 * 16 + quad * 4;
    #pragma unroll
    for (int dt = 0; dt < 4; ++dt) {
      const int row = dt * 16 + l15;
      vf[dt] = *(const s4v*)&Vt[row * 72 + (kb ^ (row & 56))];
    }
    #pragma unroll
    for (int qg = 0; qg < 2; ++qg) {
      s4v pf;
      ((unsigned int*)&pf)[0] = pk[qg][k4][0];
      ((unsigned int*)&pf)[1] = pk[qg][k4][1];
      lacc[qg] = mfma16(vones, pf, lacc[qg]);
      #pragma unroll
      for (int dt = 0; dt < 4; ++dt)
        ot[qg][dt] = mfma16(vf[dt], pf, ot[qg][dt]);
    }
  }
  __builtin_amdgcn_s_setprio(0);

  // wave-uniform deferred-max guard (never fires for this data; exact when it does)
  if (__builtin_expect(__any(mx > thr), 0)) {
    #pragma unroll
    for (int o = 1; o < 64; o <<= 1) mx = fmaxf(mx, __shfl_xor(mx, o));
    const float c = __builtin_amdgcn_exp2f(miu - mx);
    miu = mx; thr = mx + 8.f;
    #pragma unroll
    for (int qg = 0; qg < 2; ++qg) {
      lacc[qg][0] *= c; lacc[qg][1] *= c; lacc[qg][2] *= c; lacc[qg][3] *= c;
      #pragma unroll
      for (int dt = 0; dt < 4; ++dt) {
        ot[qg][dt][0] *= c; ot[qg][dt][1] *= c;
        ot[qg][dt][2] *= c; ot[qg][dt][3] *= c;
      }
    }
  }
}

__global__ __launch_bounds__(256) void k_attn(
    const unsigned short* __restrict__ qf,
    const unsigned short* __restrict__ lkv,
    unsigned short* __restrict__ attn_out,
    unsigned short* __restrict__ Opart,  // f16 normalized: [(s,qb)][q(128)][d(64)]
    float* __restrict__ mpart,
    float* __restrict__ lpart)
{
  __shared__ unsigned short smem[18432];  // 36864 B: 2 x (Ks[64][72] + Vt[64][72])
  unsigned short* const Ks0 = smem;
  unsigned short* const Vt0 = smem + 4608;
  unsigned short* const Ks1 = smem + 9216;
  unsigned short* const Vt1 = smem + 13824;

  const int tid = threadIdx.x;
  const int w = tid >> 6, lane = tid & 63;
  const int quad = lane >> 4, l15 = lane & 15;

  // T1 XCD swizzle: HW round-robins consecutive blockIdx across 8 XCDs; remap so
  // XCD x owns the CONTIGUOUS logical chunk [x*224,(x+1)*224) -> blocks sharing a
  // bh's K/V panel (32 consecutive logical IDs) hit one L2. 1792=8*224 bijective.
  const int bx = (blockIdx.x & 7) * NB_CHUNK + (blockIdx.x >> 3);

  int bh, q0tok, kstart, kt0, kt1, q0lat, s6 = 0, qb = 0;
  bool latent;
  if (bx < 256 * NSPLIT) {
    latent = true;
    qb = bx / NSPLIT;            // bh*8 + qt
    s6 = bx % NSPLIT;
    bh = qb >> 3;
    q0lat = (qb & 7) * 128;
    q0tok = NB_CTX + q0lat;
    kstart = 0;
    const int nkt = (NB_CTX + q0lat + 128) >> 6;   // always even (50..64)
    const int hk = nkt >> 1;
    kt0 = 2 * ((s6 * hk) / NSPLIT);                // even split boundaries
    kt1 = 2 * (((s6 + 1) * hk) / NSPLIT);
  } else {
    latent = false;
    int idx = bx - 256 * NSPLIT;
    bh = idx / 24;
    int r2 = idx % 24;
    int seg = r2 >> 1;
    q0lat = 0;
    q0tok = seg * 256 + (r2 & 1) * 128;
    kstart = seg * 256;
    kt0 = 0; kt1 = 4;
  }

  const unsigned short* qbase = qf + ((long)bh * NB_N + q0tok) * 64;
  const unsigned short* kbase = lkv + (long)bh * NB_N * 64;

  // Q fragments direct from global (coalesced 16B, 16 rows x 64B segments)
  short8 qfr[2][2];
  #pragma unroll
  for (int qg = 0; qg < 2; ++qg)
    #pragma unroll
    for (int kc = 0; kc < 2; ++kc)
      qfr[qg][kc] = *(const short8*)(qbase + (w * 32 + qg * 16 + l15) * 64 + kc * 32 + quad * 8);

  // staging coords: thread covers adjacent keys 2kp, 2kp+1, d-chunk sdc
  const int kp = tid >> 3, sdc = tid & 7;

  uint4 gA, gB;
  {
    const int key0 = kstart + kt0 * 64;
    gA = *(const uint4*)(kbase + (long)(key0 + 2 * kp) * 64 + sdc * 8);
    gB = *(const uint4*)(kbase + (long)(key0 + 2 * kp + 1) * 64 + sdc * 8);
  }
  stage_kv(Ks0, Vt0, kp, sdc, gA, gB);   // prologue: tile kt0 -> buf0
  {
    const int key1 = kstart + (kt0 + 1) * 64;   // kt0+1 < kt1 always (>=2 tiles)
    gA = *(const uint4*)(kbase + (long)(key1 + 2 * kp) * 64 + sdc * 8);
    gB = *(const uint4*)(kbase + (long)(key1 + 2 * kp + 1) * 64 + sdc * 8);
  }

  f32x4 ot[2][4];     // O^T in 2^-miu units: row=d (quad*4+r), col=q (l15)
  f32x4 lacc[2];      // P row-sums (all 4 elements equal), per q=l15
  float miu = 0.f, thr = 8.f;
  #pragma unroll
  for (int qg = 0; qg < 2; ++qg) {
    #pragma unroll
    for (int dt = 0; dt < 4; ++dt) ot[qg][dt] = (f32x4){0.f, 0.f, 0.f, 0.f};
    lacc[qg] = (f32x4){0.f, 0.f, 0.f, 0.f};
  }

  // pair-unrolled: trip count kt1-kt0 always even -> static LDS addresses
  for (int kt = kt0; kt < kt1; kt += 2) {
    attn_tile(Ks0, Vt0, Ks1, Vt1, kt,     kt1, kstart, latent, q0lat,
              w, quad, l15, kp, sdc, kbase, gA, gB, qfr, ot, lacc, miu, thr);
    attn_tile(Ks1, Vt1, Ks0, Vt0, kt + 1, kt1, kstart, latent, q0lat,
              w, quad, l15, kp, sdc, kbase, gA, gB, qfr, ot, lacc, miu, thr);
  }

  __syncthreads();   // all waves done reading Ks/Vt
  if (latent) {
    const long pb = (long)(s6 * 256 + qb);
    if (quad == 0) {
      #pragma unroll
      for (int qg = 0; qg < 2; ++qg) {
        mpart[pb * 128 + w * 32 + qg * 16 + l15] = miu;
        lpart[pb * 128 + w * 32 + qg * 16 + l15] = lacc[qg][0];
      }
    }
    // normalized O/l as f16, [q][d] layout: 8B store per (qg,dt)
    unsigned short* obase = Opart + pb * 8192;
    #pragma unroll
    for (int qg = 0; qg < 2; ++qg) {
      const float inv = 1.0f / lacc[qg][0];
      const int q = w * 32 + qg * 16 + l15;
      #pragma unroll
      for (int dt = 0; dt < 4; ++dt) {
        uint2 u;
        u.x = pkh(ot[qg][dt][0] * inv, ot[qg][dt][1] * inv);
        u.y = pkh(ot[qg][dt][2] * inv, ot[qg][dt][3] * inv);
        *(uint2*)&obase[q * 64 + dt * 16 + quad * 4] = u;
      }
    }
  } else {
    // normalize, transpose via LDS (overlay [128][72] shorts), coalesced store
    #pragma unroll
    for (int qg = 0; qg < 2; ++qg) {
      const float inv = 1.0f / lacc[qg][0];
      const int q = w * 32 + qg * 16 + l15;
      #pragma unroll
      for (int dt = 0; dt < 4; ++dt)
        #pragma unroll
        for (int r = 0; r < 4; ++r)
          smem[q * 72 + dt * 16 + quad * 4 + r] = f2bf(ot[qg][dt][r] * inv);
    }
    __syncthreads();
    const int qrow = tid >> 1, half = tid & 1;
    const int b_ = bh >> 4, h_ = bh & 15;
    unsigned short* orow = attn_out + ((long)b_ * NB_N + q0tok + qrow) * NB_DIM + h_ * 64 + half * 32;
    #pragma unroll
    for (int v = 0; v < 4; ++v)
      *(uint4*)(orow + v * 8) = *(const uint4*)&smem[qrow * 72 + half * 32 + v * 8];
  }
}

// ---------------- combine latent split-K partials (f16 normalized [q][d] layout) ------
// out[q][d] = sum_s w_s * o_s[q][d] / sum_s w_s,  w_s = 2^(m_s - m*) * l_s.
// No LDS, no barrier: [q][d] layout makes both the reads and the bf16 output
// stores directly coalesced.
__global__ __launch_bounds__(256) void k_combine(
    const unsigned short* __restrict__ Opart, const float* __restrict__ mpart,
    const float* __restrict__ lpart, unsigned short* __restrict__ attn_out)
{
  const int qb = blockIdx.x;             // bh*8 + qt
  const int bh = qb >> 3, qt = qb & 7;
  const int b = bh >> 4, h = bh & 15;
  const int t = threadIdx.x;
  const int q = t >> 1;                  // 128 q rows
  const int dh = (t & 1) * 32;           // half of the 64-wide head dim

  float m[NSPLIT], l[NSPLIT], mstar = NEGF;
  #pragma unroll
  for (int s = 0; s < NSPLIT; ++s) {
    m[s] = mpart[(s * 256 + qb) * 128 + q];
    l[s] = lpart[(s * 256 + qb) * 128 + q];
    mstar = fmaxf(mstar, m[s]);
  }
  float wsum = 0.f, ws[NSPLIT];
  #pragma unroll
  for (int s = 0; s < NSPLIT; ++s) {
    ws[s] = __builtin_amdgcn_exp2f(m[s] - mstar) * l[s];
    wsum += ws[s];
  }
  const float inv = 1.0f / wsum;

  float acc[32];
  #pragma unroll
  for (int d = 0; d < 32; ++d) acc[d] = 0.f;

  #pragma unroll
  for (int s = 0; s < NSPLIT; ++s) {
    const unsigned short* base = Opart + ((long)(s * 256 + qb)) * 8192 + q * 64 + dh;
    const float wv = ws[s];
    #pragma unroll
    for (int v = 0; v < 4; ++v) {
      uint4 u = *(const uint4*)(base + v * 8);
      const unsigned int uw[4] = {u.x, u.y, u.z, u.w};
      #pragma unroll
      for (int e = 0; e < 4; ++e) {
        union { unsigned int u; fp16x2 h; } cv; cv.u = uw[e];
        acc[v * 8 + e * 2]     += wv * (float)cv.h[0];
        acc[v * 8 + e * 2 + 1] += wv * (float)cv.h[1];
      }
    }
  }

  unsigned short* orow = attn_out + ((long)b * NB_N + NB_CTX + qt * 128 + q) * NB_DIM + h * 64 + dh;
  #pragma unroll
  for (int v = 0; v < 4; ++v) {
    uint4 u;
    u.x = (unsigned)f2bf(acc[v * 8 + 0] * inv) | ((unsigned)f2bf(acc[v * 8 + 1] * inv) << 16);
    u.y = (unsigned)f2bf(acc[v * 8 + 2] * inv) | ((unsigned)f2bf(acc[v * 8 + 3] * inv) << 16);
    u.z = (unsigned)f2bf(acc[v * 8 + 4] * inv) | ((unsigned)f2bf(acc[v * 8 + 5] * inv) << 16);
    u.w = (unsigned)f2bf(acc[v * 8 + 6] * inv) | ((unsigned)f2bf(acc[v * 8 + 7] * inv) << 16);
    *(uint4*)(orow + v * 8) = u;
  }
}

extern "C" void kernel_launch(void* const* d_in, const int* in_sizes, int n_in,
                              void* d_out, int out_size, void* d_ws, size_t ws_size,
                              hipStream_t stream)
{
  const float* x    = (const float*)d_in[0];
  const float* Wq   = (const float*)d_in[1];
  const float* Wkv  = (const float*)d_in[2];
  const float* Wo   = (const float*)d_in[3];
  const float* bo   = (const float*)d_in[4];
  const float* ln_g = (const float*)d_in[5];
  const float* ln_b = (const float*)d_in[6];
  float* out = (float*)d_out;

  char* ws = (char*)d_ws;
  unsigned short* xb    = (unsigned short*)(ws);                       // [0,16M)
  unsigned short* WqkvT = (unsigned short*)(ws + (size_t)(16 << 20));  // [16,20M)
  unsigned short* WoT   = (unsigned short*)(ws + (size_t)(20 << 20));  // [20,22M)
  float2*         tab   = (float2*)        (ws + (size_t)(22 << 20));  // [22,23M)
  unsigned short* qfb   = (unsigned short*)(ws + (size_t)(24 << 20));  // [24,40M)
  unsigned short* lkv   = (unsigned short*)(ws + (size_t)(40 << 20));  // [40,56M)
  unsigned short* aout  = (unsigned short*)(ws + (size_t)(56 << 20));  // [56,72M)
  unsigned short* Opart = (unsigned short*)(ws + (size_t)(72 << 20));  // [72,89M) f16
  float*          mpart = (float*)         (ws + (size_t)(112 << 20)); // [112,113M)
  float*          lpart = (float*)         (ws + (size_t)(113 << 20)); // [113,114M)

  hipLaunchKernelGGL(k_prep, dim3(3328), dim3(256), 0, stream,
                     x, Wq, Wkv, Wo, xb, WqkvT, WoT, tab);
  hipLaunchKernelGGL(k_gemm_qkv, dim3(16, 64), dim3(256), 0, stream,
                     xb, WqkvT, qfb, lkv, tab, ln_g, ln_b);
  hipLaunchKernelGGL(k_attn, dim3(NB_GRID), dim3(256), 0, stream,
                     qfb, lkv, aout, Opart, mpart, lpart);
  hipLaunchKernelGGL(k_combine, dim3(256), dim3(256), 0, stream,
                     Opart, mpart, lpart, aout);
  hipLaunchKernelGGL(k_gemm_bt, dim3(8, 64), dim3(256), 0, stream,
                     aout, WoT, out, bo, 1024, 1024);
}

// Round 14
// 257.392 us; speedup vs baseline: 1.1603x; 1.1603x over previous
//
#include <hip/hip_runtime.h>
#include <math.h>

#define NB_B 2
#define NB_N 4096
#define NB_DIM 1024
#define NB_H 16
#define NB_D 64
#define NB_CTX 3072
#define NSPLIT 4
// 0.125 * log2(e): folds softmax base-2 conversion into q scale
#define QSCALE 0.18033688011112042f
#define NEGF -3.0e38f

typedef __attribute__((ext_vector_type(8))) short short8;
typedef __attribute__((ext_vector_type(4))) short s4v;
typedef __attribute__((ext_vector_type(4))) float f32x4;
typedef __fp16 fp16x2 __attribute__((ext_vector_type(2)));

#if __has_builtin(__builtin_amdgcn_mfma_f32_16x16x16bf16_1k)
__device__ __forceinline__ f32x4 mfma16(s4v a, s4v b, f32x4 c) {
  return __builtin_amdgcn_mfma_f32_16x16x16bf16_1k(a, b, c, 0, 0, 0);
}
#else
__device__ __forceinline__ f32x4 mfma16(s4v a, s4v b, f32x4 c) {
  f32x4 d;
  asm volatile("v_mfma_f32_16x16x16_bf16 %0, %1, %2, %3"
               : "=v"(d) : "v"(a), "v"(b), "v"(c));
  return d;
}
#endif

__device__ __forceinline__ unsigned short f2bf(float f) {
  union { float f; unsigned u; } v; v.f = f;
  unsigned r = v.u + 0x7fffu + ((v.u >> 16) & 1u);
  return (unsigned short)(r >> 16);
}

// packed f32x2 -> bf16x2 (RNE), 1 op instead of and/and/perm
__device__ __forceinline__ unsigned int cvtpk(float a, float b) {
  unsigned int r;
  asm("v_cvt_pk_bf16_f32 %0, %1, %2" : "=v"(r) : "v"(a), "v"(b));
  return r;
}

// packed f32x2 -> f16x2 (RTZ)
__device__ __forceinline__ unsigned int pkh(float a, float b) {
  union { fp16x2 h; unsigned int u; } cv;
  cv.h = __builtin_amdgcn_cvt_pkrtz(a, b);
  return cv.u;
}

__device__ __forceinline__ void async16(const void* g, void* l) {
  typedef const unsigned int __attribute__((address_space(1)))* gas_t;
  typedef unsigned int __attribute__((address_space(3)))* las_t;
  __builtin_amdgcn_global_load_lds((gas_t)(unsigned long long)g,
                                   (las_t)(unsigned)(unsigned long long)l,
                                   16, 0, 0);
}

// ---------------- merged prep: conv_x | weight transpose | rope table ----------------
__global__ __launch_bounds__(256) void k_prep(
    const float* __restrict__ x,
    const float* __restrict__ Wq, const float* __restrict__ Wkv, const float* __restrict__ Wo,
    unsigned short* __restrict__ xb, unsigned short* __restrict__ WqkvT,
    unsigned short* __restrict__ WoT, float2* __restrict__ tab)
{
  __shared__ float tile[64][65];
  const int bx = blockIdx.x, tid = threadIdx.x;
  if (bx < 2048) {
    const float4* x4 = (const float4*)x;
    ushort4* xb4 = (ushort4*)xb;
    const int n4 = (NB_B * NB_N * NB_DIM) / 4;
    for (int i = bx * 256 + tid; i < n4; i += 2048 * 256) {
      float4 v = x4[i];
      ushort4 o;
      o.x = f2bf(v.x); o.y = f2bf(v.y); o.z = f2bf(v.z); o.w = f2bf(v.w);
      xb4[i] = o;
    }
  } else if (bx < 2816) {
    int idx = bx - 2048;
    int z = idx >> 8, rem = idx & 255;
    const float* W; unsigned short* out;
    if (z == 0)      { W = Wq;  out = WqkvT; }
    else if (z == 1) { W = Wkv; out = WqkvT + 1024 * 1024; }
    else             { W = Wo;  out = WoT; }
    int c0 = (rem & 15) * 64, k0 = (rem >> 4) * 64;
    int tx = tid & 63, ty = tid >> 6;
    #pragma unroll
    for (int i = 0; i < 16; ++i) {
      int k = ty + i * 4;
      tile[k][tx] = W[(long)(k0 + k) * 1024 + c0 + tx];
    }
    __syncthreads();
    #pragma unroll
    for (int i = 0; i < 16; ++i) {
      int c = ty + i * 4;
      out[(long)(c0 + c) * 1024 + k0 + tx] = f2bf(tile[tx][c]);
    }
  } else {
    int idx = (bx - 2816) * 256 + tid;   // [0, 131072)
    int n = idx >> 5, fi = idx & 31;
    float inv = exp2f(-(float)fi * (13.287712379549449f / 32.0f));
    float ang = (float)n * inv;
    float s, c;
    sincosf(ang, &s, &c);
    tab[idx] = make_float2(c, s);
  }
}

// ---------------- QKV GEMM, 2-phase double-buffered LDS (T3/T4 minimum) ----------------
__global__ __launch_bounds__(256) void k_gemm_qkv(
    const unsigned short* __restrict__ A,
    const unsigned short* __restrict__ Bt,
    unsigned short* __restrict__ qf,
    unsigned short* __restrict__ lkvp,
    const float2* __restrict__ tab,
    const float* __restrict__ ln_g,
    const float* __restrict__ ln_b)
{
  __shared__ unsigned short As[2][128 * 32];
  __shared__ unsigned short Bs[2][128 * 32];
  const int tid = threadIdx.x;
  const int w = tid >> 6, lane = tid & 63;
  const int wr = w >> 1, wc = w & 1;
  const int quad = lane >> 4, l15 = lane & 15;
  const long tm = (long)blockIdx.y * 128, tn = (long)blockIdx.x * 128;
  const int K = 1024;

  f32x4 acc[4][4];
  #pragma unroll
  for (int i = 0; i < 4; ++i)
    #pragma unroll
    for (int j = 0; j < 4; ++j)
      acc[i][j] = (f32x4){0.f, 0.f, 0.f, 0.f};

  const unsigned short* Ag0 = A + (tm + w * 16 + (lane >> 2)) * K + (lane & 3) * 8;
  const unsigned short* Bg0 = Bt + (tn + w * 16 + (lane >> 2)) * K + (lane & 3) * 8;
  const unsigned short* Ag1 = Ag0 + (long)64 * K;
  const unsigned short* Bg1 = Bg0 + (long)64 * K;
  const int so0 = (w * 16) * 32;          // this wave's slab offsets within a buffer
  const int so1 = (64 + w * 16) * 32;

#define QKV_STAGE(b, k)                         \
  async16(Ag0 + (k), &As[b][so0]);              \
  async16(Ag1 + (k), &As[b][so1]);              \
  async16(Bg0 + (k), &Bs[b][so0]);              \
  async16(Bg1 + (k), &Bs[b][so1]);

#define QKV_CONSUME(b)                                                          \
  {                                                                             \
    short8 af[4], bfr[4];                                                       \
    _Pragma("unroll")                                                           \
    for (int i = 0; i < 4; ++i)                                                 \
      af[i] = *(const short8*)&As[b][(wr * 64 + i * 16 + l15) * 32 + quad * 8]; \
    _Pragma("unroll")                                                           \
    for (int j = 0; j < 4; ++j)                                                 \
      bfr[j] = *(const short8*)&Bs[b][(wc * 64 + j * 16 + l15) * 32 + quad * 8];\
    __builtin_amdgcn_s_setprio(1);                                              \
    _Pragma("unroll")                                                           \
    for (int i = 0; i < 4; ++i)                                                 \
      _Pragma("unroll")                                                         \
      for (int j = 0; j < 4; ++j)                                               \
        acc[i][j] = __builtin_amdgcn_mfma_f32_16x16x32_bf16(af[i], bfr[j], acc[i][j], 0, 0, 0); \
    __builtin_amdgcn_s_setprio(0);                                              \
  }

  QKV_STAGE(0, 0);                        // prologue: first slab -> buf0
  for (int k0 = 0; k0 < K; k0 += 64) {
    __syncthreads();                      // buf0 staged loads drained; buf1 reads done
    if (k0 + 32 < K) { QKV_STAGE(1, k0 + 32); }
    QKV_CONSUME(0);
    __syncthreads();                      // buf1 staged loads drained; buf0 reads done
    if (k0 + 64 < K) { QKV_STAGE(0, k0 + 64); }
    QKV_CONSUME(1);
  }

  const int col_base = (int)tn + wc * 64;
  const bool is_q = col_base < 1024;
  const int hh = (col_base & 1023) >> 6;
  unsigned short* dst = is_q ? qf : lkvp;
  float g_ln[4], b_ln[4];
  #pragma unroll
  for (int j = 0; j < 4; ++j) { g_ln[j] = ln_g[j * 16 + l15]; b_ln[j] = ln_b[j * 16 + l15]; }

  const int row_base = (int)tm + wr * 64;
  #pragma unroll
  for (int i = 0; i < 4; ++i) {
    #pragma unroll
    for (int r = 0; r < 4; ++r) {
      const int row = row_base + i * 16 + quad * 4 + r;
      const int n = row & 4095, b = row >> 12;
      const float2 cs0 = tab[n * 32 + l15];
      const float2 cs1 = tab[n * 32 + 16 + l15];
      float val[4];
      #pragma unroll
      for (int j = 0; j < 4; ++j) {
        float t = acc[i][j][r], pt = acc[i][j ^ 2][r];
        float2 cs = (j & 1) ? cs1 : cs0;
        float rot = (j < 2) ? -pt : pt;
        val[j] = t * cs.x + rot * cs.y;
      }
      unsigned short* orow = dst + ((long)(b * 16 + hh) * NB_N + n) * 64;
      if (is_q) {
        #pragma unroll
        for (int j = 0; j < 4; ++j)
          orow[j * 16 + l15] = f2bf(val[j] * QSCALE);
      } else {
        float s = val[0] + val[1] + val[2] + val[3];
        #pragma unroll
        for (int o = 1; o < 16; o <<= 1) s += __shfl_xor(s, o);
        const float mu = s * 0.015625f;
        float dv[4], vs = 0.f;
        #pragma unroll
        for (int j = 0; j < 4; ++j) { dv[j] = val[j] - mu; vs += dv[j] * dv[j]; }
        #pragma unroll
        for (int o = 1; o < 16; o <<= 1) vs += __shfl_xor(vs, o);
        const float rr = rsqrtf(vs * 0.015625f + 1e-5f);
        #pragma unroll
        for (int j = 0; j < 4; ++j)
          orow[j * 16 + l15] = f2bf(dv[j] * rr * g_ln[j] + b_ln[j]);
      }
    }
  }
}

// ---------------- generic bf16 GEMM (final projection), 2-phase dbuf ----------------
__global__ __launch_bounds__(256) void k_gemm_bt(
    const unsigned short* __restrict__ A,
    const unsigned short* __restrict__ Bt,
    float* __restrict__ C,
    const float* __restrict__ bias,
    int K, int ldc)
{
  __shared__ unsigned short As[2][128 * 32];
  __shared__ unsigned short Bs[2][128 * 32];
  const int tid = threadIdx.x;
  const int w = tid >> 6, lane = tid & 63;
  const int wr = w >> 1, wc = w & 1;
  const int quad = lane >> 4, l15 = lane & 15;
  const long tm = (long)blockIdx.y * 128, tn = (long)blockIdx.x * 128;

  f32x4 acc[4][4];
  #pragma unroll
  for (int i = 0; i < 4; ++i)
    #pragma unroll
    for (int j = 0; j < 4; ++j)
      acc[i][j] = (f32x4){0.f, 0.f, 0.f, 0.f};

  const unsigned short* Ag0 = A + (tm + w * 16 + (lane >> 2)) * K + (lane & 3) * 8;
  const unsigned short* Bg0 = Bt + (tn + w * 16 + (lane >> 2)) * K + (lane & 3) * 8;
  const unsigned short* Ag1 = Ag0 + (long)64 * K;
  const unsigned short* Bg1 = Bg0 + (long)64 * K;
  const int so0 = (w * 16) * 32;
  const int so1 = (64 + w * 16) * 32;

  QKV_STAGE(0, 0);
  for (int k0 = 0; k0 < K; k0 += 64) {
    __syncthreads();
    if (k0 + 32 < K) { QKV_STAGE(1, k0 + 32); }
    QKV_CONSUME(0);
    __syncthreads();
    if (k0 + 64 < K) { QKV_STAGE(0, k0 + 64); }
    QKV_CONSUME(1);
  }

  #pragma unroll
  for (int j = 0; j < 4; ++j) {
    const long col = tn + wc * 64 + j * 16 + l15;
    const float bv = bias ? bias[col] : 0.0f;
    #pragma unroll
    for (int i = 0; i < 4; ++i) {
      #pragma unroll
      for (int r = 0; r < 4; ++r) {
        const long row = tm + wr * 64 + i * 16 + quad * 4 + r;
        C[row * ldc + col] = acc[i][j][r] + bv;
      }
    }
  }
}

// ---------------- flash attention + per-segment balanced XCD swizzle ----------------
// Round-13 lesson: whole-grid chunking localized K/V (FETCH 47->23 MB) but gave
// long-latent chunks to some XCDs and short-context chunks to others -> idle
// XCDs. Fix: chunk LATENT (1024 = 8*128) and CONTEXT (768 = 8*96) separately.
// XCD x now gets 4 complete latent bh-groups (equal tile counts on every XCD)
// plus the 96 context blocks of the SAME 4 bh's K/V panels (~2 MB, L2-fit).

#define NB_GRID (256 * NSPLIT + 768)     // 1792

__device__ __forceinline__ void stage_kv(
    unsigned short* __restrict__ Ksn, unsigned short* __restrict__ Vtn,
    const int kp, const int sdc, const uint4& gA, const uint4& gB)
{
  *(uint4*)&Ksn[(2 * kp) * 72 + sdc * 8] = gA;
  *(uint4*)&Ksn[(2 * kp + 1) * 72 + sdc * 8] = gB;
  const unsigned int* wA = (const unsigned int*)&gA;
  const unsigned int* wB = (const unsigned int*)&gB;
  #pragma unroll
  for (int jw = 0; jw < 4; ++jw) {
    const unsigned int lo = __builtin_amdgcn_perm(wB[jw], wA[jw], 0x05040100u);
    const unsigned int hi = __builtin_amdgcn_perm(wB[jw], wA[jw], 0x07060302u);
    const int d0 = sdc * 8 + jw * 2;
    const int xo = (2 * kp) ^ (d0 & 56);   // (d0+1)&56 == d0&56 (d0 even)
    *(unsigned int*)&Vtn[d0 * 72 + xo] = lo;
    *(unsigned int*)&Vtn[(d0 + 1) * 72 + xo] = hi;
  }
}

#define NB_PACK(QG, SUB)                                               \
  _Pragma("unroll")                                                    \
  for (int k4 = 0; k4 < 4; ++k4) {                                     \
    const float p0 = __builtin_amdgcn_exp2f(st[QG][k4][0] SUB);        \
    const float p1 = __builtin_amdgcn_exp2f(st[QG][k4][1] SUB);        \
    const float p2 = __builtin_amdgcn_exp2f(st[QG][k4][2] SUB);        \
    const float p3 = __builtin_amdgcn_exp2f(st[QG][k4][3] SUB);        \
    pk[QG][k4][0] = cvtpk(p0, p1);                                     \
    pk[QG][k4][1] = cvtpk(p2, p3);                                     \
  }

__device__ __forceinline__ void attn_tile(
    const unsigned short* __restrict__ Ks, const unsigned short* __restrict__ Vt,
    unsigned short* __restrict__ Ksn, unsigned short* __restrict__ Vtn,
    const int kt, const int kt1, const int kstart, const bool latent, const int q0lat,
    const int w, const int quad, const int l15, const int kp, const int sdc,
    const unsigned short* __restrict__ kbase,
    uint4& gA, uint4& gB, const short8 (&qfr)[2][2],
    f32x4 (&ot)[2][4], f32x4 (&lacc)[2], float& miu, float& thr)
{
  const int key0 = kstart + kt * 64;
  __syncthreads();   // buf[cur] staged stores visible; buf[next] reads complete

  if (kt + 1 < kt1) {   // stage next tile into the OTHER buffer (drains under compute)
    stage_kv(Ksn, Vtn, kp, sdc, gA, gB);
    if (kt + 2 < kt1) { // prefetch tile kt+2 into regs
      const long k2 = (long)(key0 + 128);
      gA = *(const uint4*)(kbase + (k2 + 2 * kp) * 64 + sdc * 8);
      gB = *(const uint4*)(kbase + (k2 + 2 * kp + 1) * 64 + sdc * 8);
    }
  }

  // S^T[key][q]
  f32x4 st[2][4];
  #pragma unroll
  for (int qg = 0; qg < 2; ++qg)
    #pragma unroll
    for (int k4 = 0; k4 < 4; ++k4)
      st[qg][k4] = (f32x4){0.f, 0.f, 0.f, 0.f};
  __builtin_amdgcn_s_setprio(1);
  #pragma unroll
  for (int kc = 0; kc < 2; ++kc) {
    short8 kf[4];
    #pragma unroll
    for (int k4 = 0; k4 < 4; ++k4)
      kf[k4] = *(const short8*)&Ks[(k4 * 16 + l15) * 72 + kc * 32 + quad * 8];
    #pragma unroll
    for (int qg = 0; qg < 2; ++qg)
      #pragma unroll
      for (int k4 = 0; k4 < 4; ++k4)
        st[qg][k4] = __builtin_amdgcn_mfma_f32_16x16x32_bf16(kf[k4], qfr[qg][kc], st[qg][k4], 0, 0, 0);
  }
  __builtin_amdgcn_s_setprio(0);

  // causal mask among latents
  if (latent && key0 + 63 >= NB_CTX) {
    #pragma unroll
    for (int qg = 0; qg < 2; ++qg) {
      const int qrow = q0lat + w * 32 + qg * 16 + l15;
      #pragma unroll
      for (int k4 = 0; k4 < 4; ++k4)
        #pragma unroll
        for (int r = 0; r < 4; ++r) {
          const int kl = key0 + k4 * 16 + quad * 4 + r - NB_CTX;
          if (kl > qrow) st[qg][k4][r] = NEGF;
        }
    }
  }

  // tile max (guard only; off the exp->PV critical path)
  float mx = st[0][0][0];
  #pragma unroll
  for (int qg = 0; qg < 2; ++qg)
    #pragma unroll
    for (int k4 = 0; k4 < 4; ++k4)
      mx = fmaxf(mx, fmaxf(fmaxf(st[qg][k4][0], st[qg][k4][1]),
                           fmaxf(st[qg][k4][2], st[qg][k4][3])));

  // exp2 against wave-uniform reference; pack to bf16 pairs via cvt_pk
  unsigned int pk[2][4][2];
  if (miu == 0.f) {
    NB_PACK(0, )
    NB_PACK(1, )
  } else {
    NB_PACK(0, - miu)
    NB_PACK(1, - miu)
  }

  // O^T += V^T P^T ; li row-sums via ones-A MFMA (sums the same bf16 P)
  const s4v vones = { (short)0x3F80, (short)0x3F80, (short)0x3F80, (short)0x3F80 };
  __builtin_amdgcn_s_setprio(1);
  #pragma unroll
  for (int k4 = 0; k4 < 4; ++k4) {
    s4v vf[4];
    const int kb = k4 * 16 + quad * 4;
    #pragma unroll
    for (int dt = 0; dt < 4; ++dt) {
      const int row = dt * 16 + l15;
      vf[dt] = *(const s4v*)&Vt[row * 72 + (kb ^ (row & 56))];
    }
    #pragma unroll
    for (int qg = 0; qg < 2; ++qg) {
      s4v pf;
      ((unsigned int*)&pf)[0] = pk[qg][k4][0];
      ((unsigned int*)&pf)[1] = pk[qg][k4][1];
      lacc[qg] = mfma16(vones, pf, lacc[qg]);
      #pragma unroll
      for (int dt = 0; dt < 4; ++dt)
        ot[qg][dt] = mfma16(vf[dt], pf, ot[qg][dt]);
    }
  }
  __builtin_amdgcn_s_setprio(0);

  // wave-uniform deferred-max guard (never fires for this data; exact when it does)
  if (__builtin_expect(__any(mx > thr), 0)) {
    #pragma unroll
    for (int o = 1; o < 64; o <<= 1) mx = fmaxf(mx, __shfl_xor(mx, o));
    const float c = __builtin_amdgcn_exp2f(miu - mx);
    miu = mx; thr = mx + 8.f;
    #pragma unroll
    for (int qg = 0; qg < 2; ++qg) {
      lacc[qg][0] *= c; lacc[qg][1] *= c; lacc[qg][2] *= c; lacc[qg][3] *= c;
      #pragma unroll
      for (int dt = 0; dt < 4; ++dt) {
        ot[qg][dt][0] *= c; ot[qg][dt][1] *= c;
        ot[qg][dt][2] *= c; ot[qg][dt][3] *= c;
      }
    }
  }
}

__global__ __launch_bounds__(256) void k_attn(
    const unsigned short* __restrict__ qf,
    const unsigned short* __restrict__ lkv,
    unsigned short* __restrict__ attn_out,
    unsigned short* __restrict__ Opart,  // f16 normalized: [(s,qb)][q(128)][d(64)]
    float* __restrict__ mpart,
    float* __restrict__ lpart)
{
  __shared__ unsigned short smem[18432];  // 36864 B: 2 x (Ks[64][72] + Vt[64][72])
  unsigned short* const Ks0 = smem;
  unsigned short* const Vt0 = smem + 4608;
  unsigned short* const Ks1 = smem + 9216;
  unsigned short* const Vt1 = smem + 13824;

  const int tid = threadIdx.x;
  const int w = tid >> 6, lane = tid & 63;
  const int quad = lane >> 4, l15 = lane & 15;

  // Per-segment balanced XCD swizzle: latent 1024=8*128, context 768=8*96, both
  // chunked separately so every XCD gets equal work AND contiguous bh panels.
  int bx;
  if (blockIdx.x < 1024) {
    bx = (blockIdx.x & 7) * 128 + (blockIdx.x >> 3);
  } else {
    const int ic = blockIdx.x - 1024;
    bx = 1024 + (ic & 7) * 96 + (ic >> 3);
  }

  int bh, q0tok, kstart, kt0, kt1, q0lat, s6 = 0, qb = 0;
  bool latent;
  if (bx < 256 * NSPLIT) {
    latent = true;
    qb = bx / NSPLIT;            // bh*8 + qt
    s6 = bx % NSPLIT;
    bh = qb >> 3;
    q0lat = (qb & 7) * 128;
    q0tok = NB_CTX + q0lat;
    kstart = 0;
    const int nkt = (NB_CTX + q0lat + 128) >> 6;   // always even (50..64)
    const int hk = nkt >> 1;
    kt0 = 2 * ((s6 * hk) / NSPLIT);                // even split boundaries
    kt1 = 2 * (((s6 + 1) * hk) / NSPLIT);
  } else {
    latent = false;
    int idx = bx - 256 * NSPLIT;
    bh = idx / 24;
    int r2 = idx % 24;
    int seg = r2 >> 1;
    q0lat = 0;
    q0tok = seg * 256 + (r2 & 1) * 128;
    kstart = seg * 256;
    kt0 = 0; kt1 = 4;
  }

  const unsigned short* qbase = qf + ((long)bh * NB_N + q0tok) * 64;
  const unsigned short* kbase = lkv + (long)bh * NB_N * 64;

  // Q fragments direct from global (coalesced 16B, 16 rows x 64B segments)
  short8 qfr[2][2];
  #pragma unroll
  for (int qg = 0; qg < 2; ++qg)
    #pragma unroll
    for (int kc = 0; kc < 2; ++kc)
      qfr[qg][kc] = *(const short8*)(qbase + (w * 32 + qg * 16 + l15) * 64 + kc * 32 + quad * 8);

  // staging coords: thread covers adjacent keys 2kp, 2kp+1, d-chunk sdc
  const int kp = tid >> 3, sdc = tid & 7;

  uint4 gA, gB;
  {
    const int key0 = kstart + kt0 * 64;
    gA = *(const uint4*)(kbase + (long)(key0 + 2 * kp) * 64 + sdc * 8);
    gB = *(const uint4*)(kbase + (long)(key0 + 2 * kp + 1) * 64 + sdc * 8);
  }
  stage_kv(Ks0, Vt0, kp, sdc, gA, gB);   // prologue: tile kt0 -> buf0
  {
    const int key1 = kstart + (kt0 + 1) * 64;   // kt0+1 < kt1 always (>=2 tiles)
    gA = *(const uint4*)(kbase + (long)(key1 + 2 * kp) * 64 + sdc * 8);
    gB = *(const uint4*)(kbase + (long)(key1 + 2 * kp + 1) * 64 + sdc * 8);
  }

  f32x4 ot[2][4];     // O^T in 2^-miu units: row=d (quad*4+r), col=q (l15)
  f32x4 lacc[2];      // P row-sums (all 4 elements equal), per q=l15
  float miu = 0.f, thr = 8.f;
  #pragma unroll
  for (int qg = 0; qg < 2; ++qg) {
    #pragma unroll
    for (int dt = 0; dt < 4; ++dt) ot[qg][dt] = (f32x4){0.f, 0.f, 0.f, 0.f};
    lacc[qg] = (f32x4){0.f, 0.f, 0.f, 0.f};
  }

  // pair-unrolled: trip count kt1-kt0 always even -> static LDS addresses
  for (int kt = kt0; kt < kt1; kt += 2) {
    attn_tile(Ks0, Vt0, Ks1, Vt1, kt,     kt1, kstart, latent, q0lat,
              w, quad, l15, kp, sdc, kbase, gA, gB, qfr, ot, lacc, miu, thr);
    attn_tile(Ks1, Vt1, Ks0, Vt0, kt + 1, kt1, kstart, latent, q0lat,
              w, quad, l15, kp, sdc, kbase, gA, gB, qfr, ot, lacc, miu, thr);
  }

  __syncthreads();   // all waves done reading Ks/Vt
  if (latent) {
    const long pb = (long)(s6 * 256 + qb);
    if (quad == 0) {
      #pragma unroll
      for (int qg = 0; qg < 2; ++qg) {
        mpart[pb * 128 + w * 32 + qg * 16 + l15] = miu;
        lpart[pb * 128 + w * 32 + qg * 16 + l15] = lacc[qg][0];
      }
    }
    // normalized O/l as f16, [q][d] layout: 8B store per (qg,dt)
    unsigned short* obase = Opart + pb * 8192;
    #pragma unroll
    for (int qg = 0; qg < 2; ++qg) {
      const float inv = 1.0f / lacc[qg][0];
      const int q = w * 32 + qg * 16 + l15;
      #pragma unroll
      for (int dt = 0; dt < 4; ++dt) {
        uint2 u;
        u.x = pkh(ot[qg][dt][0] * inv, ot[qg][dt][1] * inv);
        u.y = pkh(ot[qg][dt][2] * inv, ot[qg][dt][3] * inv);
        *(uint2*)&obase[q * 64 + dt * 16 + quad * 4] = u;
      }
    }
  } else {
    // normalize, transpose via LDS (overlay [128][72] shorts), coalesced store
    #pragma unroll
    for (int qg = 0; qg < 2; ++qg) {
      const float inv = 1.0f / lacc[qg][0];
      const int q = w * 32 + qg * 16 + l15;
      #pragma unroll
      for (int dt = 0; dt < 4; ++dt)
        #pragma unroll
        for (int r = 0; r < 4; ++r)
          smem[q * 72 + dt * 16 + quad * 4 + r] = f2bf(ot[qg][dt][r] * inv);
    }
    __syncthreads();
    const int qrow = tid >> 1, half = tid & 1;
    const int b_ = bh >> 4, h_ = bh & 15;
    unsigned short* orow = attn_out + ((long)b_ * NB_N + q0tok + qrow) * NB_DIM + h_ * 64 + half * 32;
    #pragma unroll
    for (int v = 0; v < 4; ++v)
      *(uint4*)(orow + v * 8) = *(const uint4*)&smem[qrow * 72 + half * 32 + v * 8];
  }
}

// ---------------- combine latent split-K partials (f16 normalized [q][d] layout) ------
__global__ __launch_bounds__(256) void k_combine(
    const unsigned short* __restrict__ Opart, const float* __restrict__ mpart,
    const float* __restrict__ lpart, unsigned short* __restrict__ attn_out)
{
  const int qb = blockIdx.x;             // bh*8 + qt
  const int bh = qb >> 3, qt = qb & 7;
  const int b = bh >> 4, h = bh & 15;
  const int t = threadIdx.x;
  const int q = t >> 1;                  // 128 q rows
  const int dh = (t & 1) * 32;           // half of the 64-wide head dim

  float m[NSPLIT], l[NSPLIT], mstar = NEGF;
  #pragma unroll
  for (int s = 0; s < NSPLIT; ++s) {
    m[s] = mpart[(s * 256 + qb) * 128 + q];
    l[s] = lpart[(s * 256 + qb) * 128 + q];
    mstar = fmaxf(mstar, m[s]);
  }
  float wsum = 0.f, ws[NSPLIT];
  #pragma unroll
  for (int s = 0; s < NSPLIT; ++s) {
    ws[s] = __builtin_amdgcn_exp2f(m[s] - mstar) * l[s];
    wsum += ws[s];
  }
  const float inv = 1.0f / wsum;

  float acc[32];
  #pragma unroll
  for (int d = 0; d < 32; ++d) acc[d] = 0.f;

  #pragma unroll
  for (int s = 0; s < NSPLIT; ++s) {
    const unsigned short* base = Opart + ((long)(s * 256 + qb)) * 8192 + q * 64 + dh;
    const float wv = ws[s];
    #pragma unroll
    for (int v = 0; v < 4; ++v) {
      uint4 u = *(const uint4*)(base + v * 8);
      const unsigned int uw[4] = {u.x, u.y, u.z, u.w};
      #pragma unroll
      for (int e = 0; e < 4; ++e) {
        union { unsigned int u; fp16x2 h; } cv; cv.u = uw[e];
        acc[v * 8 + e * 2]     += wv * (float)cv.h[0];
        acc[v * 8 + e * 2 + 1] += wv * (float)cv.h[1];
      }
    }
  }

  unsigned short* orow = attn_out + ((long)b * NB_N + NB_CTX + qt * 128 + q) * NB_DIM + h * 64 + dh;
  #pragma unroll
  for (int v = 0; v < 4; ++v) {
    uint4 u;
    u.x = (unsigned)f2bf(acc[v * 8 + 0] * inv) | ((unsigned)f2bf(acc[v * 8 + 1] * inv) << 16);
    u.y = (unsigned)f2bf(acc[v * 8 + 2] * inv) | ((unsigned)f2bf(acc[v * 8 + 3] * inv) << 16);
    u.z = (unsigned)f2bf(acc[v * 8 + 4] * inv) | ((unsigned)f2bf(acc[v * 8 + 5] * inv) << 16);
    u.w = (unsigned)f2bf(acc[v * 8 + 6] * inv) | ((unsigned)f2bf(acc[v * 8 + 7] * inv) << 16);
    *(uint4*)(orow + v * 8) = u;
  }
}

extern "C" void kernel_launch(void* const* d_in, const int* in_sizes, int n_in,
                              void* d_out, int out_size, void* d_ws, size_t ws_size,
                              hipStream_t stream)
{
  const float* x    = (const float*)d_in[0];
  const float* Wq   = (const float*)d_in[1];
  const float* Wkv  = (const float*)d_in[2];
  const float* Wo   = (const float*)d_in[3];
  const float* bo   = (const float*)d_in[4];
  const float* ln_g = (const float*)d_in[5];
  const float* ln_b = (const float*)d_in[6];
  float* out = (float*)d_out;

  char* ws = (char*)d_ws;
  unsigned short* xb    = (unsigned short*)(ws);                       // [0,16M)
  unsigned short* WqkvT = (unsigned short*)(ws + (size_t)(16 << 20));  // [16,20M)
  unsigned short* WoT   = (unsigned short*)(ws + (size_t)(20 << 20));  // [20,22M)
  float2*         tab   = (float2*)        (ws + (size_t)(22 << 20));  // [22,23M)
  unsigned short* qfb   = (unsigned short*)(ws + (size_t)(24 << 20));  // [24,40M)
  unsigned short* lkv   = (unsigned short*)(ws + (size_t)(40 << 20));  // [40,56M)
  unsigned short* aout  = (unsigned short*)(ws + (size_t)(56 << 20));  // [56,72M)
  unsigned short* Opart = (unsigned short*)(ws + (size_t)(72 << 20));  // [72,89M) f16
  float*          mpart = (float*)         (ws + (size_t)(112 << 20)); // [112,113M)
  float*          lpart = (float*)         (ws + (size_t)(113 << 20)); // [113,114M)

  hipLaunchKernelGGL(k_prep, dim3(3328), dim3(256), 0, stream,
                     x, Wq, Wkv, Wo, xb, WqkvT, WoT, tab);
  hipLaunchKernelGGL(k_gemm_qkv, dim3(16, 64), dim3(256), 0, stream,
                     xb, WqkvT, qfb, lkv, tab, ln_g, ln_b);
  hipLaunchKernelGGL(k_attn, dim3(NB_GRID), dim3(256), 0, stream,
                     qfb, lkv, aout, Opart, mpart, lpart);
  hipLaunchKernelGGL(k_combine, dim3(256), dim3(256), 0, stream,
                     Opart, mpart, lpart, aout);
  hipLaunchKernelGGL(k_gemm_bt, dim3(8, 64), dim3(256), 0, stream,
                     aout, WoT, out, bo, 1024, 1024);
}